// Round 1
// baseline (537.214 us; speedup 1.0000x reference)
//
#include <hip/hip_runtime.h>

#define SLOPE 0.01f

typedef float f32x4 __attribute__((ext_vector_type(4)));

// Weight pointers passed by value as kernel args (kernarg segment).
// 20 pointers = 160 B, far under the 4 KB kernarg limit. The layer loop is
// fully unrolled, so h.w[L]/h.b[L] are compile-time kernarg offsets ->
// uniform pointers -> weight reads are scalar/broadcast cached loads.
struct Half5 { const float* w[5]; const float* b[5]; };
struct WPtrs { Half5 logs; Half5 aff; };

// 5-layer 8->8 MLP, leaky ReLU after first 4 layers.
// w[L]: 64 fp32 row-major (out[j] += w[j*8+k] * x[k]); b[L]: 8 fp32.
__device__ __forceinline__ void mlp8(const Half5& h, const float x[8], float out[8]) {
    float a[8];
    #pragma unroll
    for (int j = 0; j < 8; ++j) a[j] = x[j];
    #pragma unroll
    for (int L = 0; L < 5; ++L) {
        const float* __restrict__ wl = h.w[L];
        const float* __restrict__ bl = h.b[L];
        float t[8];
        #pragma unroll
        for (int j = 0; j < 8; ++j) {
            float acc = bl[j];
            #pragma unroll
            for (int k = 0; k < 8; ++k)
                acc = fmaf(wl[j * 8 + k], a[k], acc);
            t[j] = acc;
        }
        #pragma unroll
        for (int j = 0; j < 8; ++j)
            a[j] = (L < 4) ? fmaxf(t[j], SLOPE * t[j]) : t[j];
    }
    #pragma unroll
    for (int j = 0; j < 8; ++j) out[j] = a[j];
}

__global__ void __launch_bounds__(256)
coupling_kernel(const f32x4* __restrict__ z,   // 4 x f32x4 per row (16 fp32)
                WPtrs p,
                f32x4* __restrict__ out,
                int batch) {
    int idx = blockIdx.x * blockDim.x + threadIdx.x;
    if (idx >= batch) return;

    size_t base = (size_t)idx * 4;
    // Streaming data, touched exactly once -> nontemporal (skip L2/L3 pollution).
    f32x4 r0 = __builtin_nontemporal_load(z + base + 0);   // zl[0..3]
    f32x4 r1 = __builtin_nontemporal_load(z + base + 1);   // zl[4..7]
    f32x4 r2 = __builtin_nontemporal_load(z + base + 2);   // zr[0..3]
    f32x4 r3 = __builtin_nontemporal_load(z + base + 3);   // zr[4..7]

    float zl[8] = { r0.x, r0.y, r0.z, r0.w, r1.x, r1.y, r1.z, r1.w };
    float zr[8] = { r2.x, r2.y, r2.z, r2.w, r3.x, r3.y, r3.z, r3.w };

    float log_s[8], bb[8];
    mlp8(p.logs, zl, log_s);
    mlp8(p.aff,  zl, bb);

    float yr[8];
    #pragma unroll
    for (int k = 0; k < 8; ++k)
        yr[k] = fmaf(__expf(log_s[k]), zr[k], bb[k]);

    f32x4 o2 = { yr[0], yr[1], yr[2], yr[3] };
    f32x4 o3 = { yr[4], yr[5], yr[6], yr[7] };

    __builtin_nontemporal_store(r0, out + base + 0);   // zl pass-through (bit-exact)
    __builtin_nontemporal_store(r1, out + base + 1);
    __builtin_nontemporal_store(o2, out + base + 2);
    __builtin_nontemporal_store(o3, out + base + 3);
}

extern "C" void kernel_launch(void* const* d_in, const int* in_sizes, int n_in,
                              void* d_out, int out_size, void* d_ws, size_t ws_size,
                              hipStream_t stream) {
    const int batch = in_sizes[0] / 16;

    WPtrs p;
    if (n_in >= 21) {
        // Lists flattened into 20 separate device arrays: pass pointers directly.
        // (Replaces the previous 20x hipMemcpyAsync staging path, which cost
        //  ~330 us/launch in blit-dispatch overhead.)
        for (int i = 0; i < 5; ++i) {
            p.logs.w[i] = (const float*)d_in[1 + i];    // ws_logs[i]: 8x8
            p.logs.b[i] = (const float*)d_in[6 + i];    // bs_logs[i]: 8
            p.aff.w[i]  = (const float*)d_in[11 + i];   // ws_b[i]:    8x8
            p.aff.b[i]  = (const float*)d_in[16 + i];   // bs_b[i]:    8
        }
    } else {
        // Each list passed as one concatenated array.
        const float* wl = (const float*)d_in[1];
        const float* bl = (const float*)d_in[2];
        const float* wv = (const float*)d_in[3];
        const float* bv = (const float*)d_in[4];
        for (int i = 0; i < 5; ++i) {
            p.logs.w[i] = wl + i * 64;
            p.logs.b[i] = bl + i * 8;
            p.aff.w[i]  = wv + i * 64;
            p.aff.b[i]  = bv + i * 8;
        }
    }

    int threads = 256;
    int blocks = (batch + threads - 1) / threads;
    coupling_kernel<<<blocks, threads, 0, stream>>>(
        (const f32x4*)d_in[0], p, (f32x4*)d_out, batch);
}

// Round 2
// 428.296 us; speedup vs baseline: 1.2543x; 1.2543x over previous
//
#include <hip/hip_runtime.h>

#define SLOPE 0.01f

typedef float f32x4 __attribute__((ext_vector_type(4)));

// Weight pointers passed by value in kernarg segment (160 B). Layer loop is
// fully unrolled -> h.w[L]/h.b[L] are compile-time kernarg offsets -> uniform
// pointers -> weights come in via scalar loads and feed v_fma as SGPR operands.
struct Half5 { const float* w[5]; const float* b[5]; };
struct WPtrs { Half5 logs; Half5 aff; };

// 5-layer 8->8 MLP, leaky ReLU after first 4 layers.
// w[L]: 64 fp32 row-major (out[j] += w[j*8+k] * x[k]); b[L]: 8 fp32.
__device__ __forceinline__ void mlp8(const Half5& h, const float x[8], float out[8]) {
    float a[8];
    #pragma unroll
    for (int j = 0; j < 8; ++j) a[j] = x[j];
    #pragma unroll
    for (int L = 0; L < 5; ++L) {
        const float* __restrict__ wl = h.w[L];
        const float* __restrict__ bl = h.b[L];
        float t[8];
        #pragma unroll
        for (int j = 0; j < 8; ++j) {
            float acc = bl[j];
            #pragma unroll
            for (int k = 0; k < 8; ++k)
                acc = fmaf(wl[j * 8 + k], a[k], acc);
            t[j] = acc;
        }
        #pragma unroll
        for (int j = 0; j < 8; ++j)
            a[j] = (L < 4) ? fmaxf(t[j], SLOPE * t[j]) : t[j];
    }
    #pragma unroll
    for (int j = 0; j < 8; ++j) out[j] = a[j];
}

// Row stride in LDS floats: 16 data + 1 pad. gcd(17,32)=1 -> the per-row
// access pattern (17*l + j) cycles through all 32 banks => conflict-free;
// the corner-turn pattern (17a + 4b + j) is ~2-way (free on CDNA4).
#define ROWSTRIDE 17

__global__ void __launch_bounds__(256)
coupling_kernel(const f32x4* __restrict__ z,   // 4 x f32x4 per row (16 fp32)
                WPtrs p,
                f32x4* __restrict__ out,
                int batch) {
    // Per-wave private chunk: 64 rows x 17 floats = 4352 B; 4 waves = 17408 B.
    // No cross-wave sharing -> no __syncthreads(); same-wave LDS ordering is
    // enforced by compiler-inserted lgkmcnt waits.
    __shared__ float lds[4][64 * ROWSTRIDE];

    const int tid  = threadIdx.x;
    const int lane = tid & 63;
    const int wv   = tid >> 6;
    float* __restrict__ L = lds[wv];

    const long long waveRow0 = (long long)blockIdx.x * 256 + (long long)wv * 64;
    const long long f4base   = waveRow0 * 4;          // first float4 of this wave's chunk
    const long long f4limit  = (long long)batch * 4;
    const int a = lane >> 2;                          // row sub-index in corner turn
    const int b = lane & 3;                           // quarter-row index

    // ---- Phase 1: fully-coalesced nt loads -> LDS (corner turn in) ----
    // Each instruction: 64 lanes x 16 B contiguous = 1 KB, full 64B lines.
    #pragma unroll
    for (int i = 0; i < 4; ++i) {
        long long gi = f4base + (long long)(i * 64 + lane);
        if (gi < f4limit) {
            f32x4 v = __builtin_nontemporal_load(z + gi);
            int w0 = (i * 16 + a) * ROWSTRIDE + b * 4;
            L[w0 + 0] = v.x; L[w0 + 1] = v.y; L[w0 + 2] = v.z; L[w0 + 3] = v.w;
        }
    }

    // ---- Phase 2: each lane computes its own row out of LDS ----
    const long long row = waveRow0 + lane;
    if (row < batch) {
        const int r0 = lane * ROWSTRIDE;
        float zl[8], zr[8];
        #pragma unroll
        for (int j = 0; j < 8; ++j) zl[j] = L[r0 + j];
        #pragma unroll
        for (int j = 0; j < 8; ++j) zr[j] = L[r0 + 8 + j];

        float log_s[8], bb[8];
        mlp8(p.logs, zl, log_s);
        mlp8(p.aff,  zl, bb);

        // yr = exp(log_s) * zr + b; write back over the zr half.
        // zl half (words 0..7) stays in LDS untouched -> bit-exact passthrough.
        #pragma unroll
        for (int k = 0; k < 8; ++k)
            L[r0 + 8 + k] = fmaf(__expf(log_s[k]), zr[k], bb[k]);
    }

    // ---- Phase 3: fully-coalesced nt stores from LDS (corner turn out) ----
    #pragma unroll
    for (int i = 0; i < 4; ++i) {
        long long gi = f4base + (long long)(i * 64 + lane);
        if (gi < f4limit) {
            int w0 = (i * 16 + a) * ROWSTRIDE + b * 4;
            f32x4 v = { L[w0 + 0], L[w0 + 1], L[w0 + 2], L[w0 + 3] };
            __builtin_nontemporal_store(v, out + gi);
        }
    }
}

extern "C" void kernel_launch(void* const* d_in, const int* in_sizes, int n_in,
                              void* d_out, int out_size, void* d_ws, size_t ws_size,
                              hipStream_t stream) {
    const int batch = in_sizes[0] / 16;

    WPtrs p;
    if (n_in >= 21) {
        // Lists flattened into 20 separate device arrays: pass pointers directly.
        for (int i = 0; i < 5; ++i) {
            p.logs.w[i] = (const float*)d_in[1 + i];    // ws_logs[i]: 8x8
            p.logs.b[i] = (const float*)d_in[6 + i];    // bs_logs[i]: 8
            p.aff.w[i]  = (const float*)d_in[11 + i];   // ws_b[i]:    8x8
            p.aff.b[i]  = (const float*)d_in[16 + i];   // bs_b[i]:    8
        }
    } else {
        const float* wl = (const float*)d_in[1];
        const float* bl = (const float*)d_in[2];
        const float* wv = (const float*)d_in[3];
        const float* bv = (const float*)d_in[4];
        for (int i = 0; i < 5; ++i) {
            p.logs.w[i] = wl + i * 64;
            p.logs.b[i] = bl + i * 8;
            p.aff.w[i]  = wv + i * 64;
            p.aff.b[i]  = bv + i * 8;
        }
    }

    int threads = 256;
    int blocks = (batch + threads - 1) / threads;
    coupling_kernel<<<blocks, threads, 0, stream>>>(
        (const f32x4*)d_in[0], p, (f32x4*)d_out, batch);
}